// Round 1
// baseline (366.359 us; speedup 1.0000x reference)
//
#include <hip/hip_runtime.h>
#include <hip/hip_bf16.h>
#include <cstdint>

#define B_ 4
#define S_ 2048
#define D_ 1024
#define H_ 16
#define DK_ 64

typedef _Float16 h8 __attribute__((ext_vector_type(8)));
typedef float f32x4 __attribute__((ext_vector_type(4)));
typedef unsigned int u32x4 __attribute__((ext_vector_type(4)));

// ---------------- f32 -> f16 convert (vectorized) ----------------
__global__ __launch_bounds__(256) void conv_f16(const float* __restrict__ src,
                                                _Float16* __restrict__ dst, int n8) {
  int i = blockIdx.x * 256 + threadIdx.x;
  if (i < n8) {
    int base = i * 8;
    h8 o;
#pragma unroll
    for (int j = 0; j < 8; ++j) o[j] = (_Float16)src[base + j];
    *(h8*)(dst + base) = o;
  }
}

// ---------------- V transpose: [B,H,S,DK] -> [B,H,DK,S] ----------------
__global__ __launch_bounds__(256) void transposeV(const _Float16* __restrict__ V,
                                                  _Float16* __restrict__ Vt) {
  __shared__ unsigned short t[64][72];  // +8 pad breaks bank conflicts
  const int bid = blockIdx.x;           // B*H*(S/64) = 2048
  const int bh = bid >> 5, st = bid & 31;
  const int s0 = st * 64;
  const unsigned short* Vb = (const unsigned short*)(V + (size_t)bh * S_ * DK_) + (size_t)s0 * DK_;
  unsigned short* Vtb = (unsigned short*)(Vt + (size_t)bh * DK_ * S_) + s0;
  const int tid = threadIdx.x;
#pragma unroll
  for (int i = 0; i < 16; ++i) {
    int idx = tid + i * 256;
    int r = idx >> 6, cc = idx & 63;
    t[r][cc] = Vb[r * 64 + cc];
  }
  __syncthreads();
#pragma unroll
  for (int i = 0; i < 16; ++i) {
    int idx = tid + i * 256;
    int dk = idx >> 6, sc = idx & 63;
    Vtb[(size_t)dk * S_ + sc] = t[sc][dk];
  }
}

// ---------------- NT GEMM: C[m,n] = sum_k A[m,k]*Bw[n,k] + bias[n] ----------------
// A: [8192][1024] f16, Bw: [1024][1024] f16 (row n = output feature), K contig.
// MODE 0: write f16 into QKV layout [B,H,S,DK]; MODE 1: write f32 [M][N] (d_out).
template <int MODE>
__global__ __launch_bounds__(256) void gemm_nt(const _Float16* __restrict__ A,
                                               const _Float16* __restrict__ Bw,
                                               const float* __restrict__ bias,
                                               void* __restrict__ Cout) {
  constexpr int K = D_;  // 1024
  __shared__ unsigned short lds[2 * 128 * 64];
  char* ldsA = (char*)lds;
  char* ldsB = (char*)(lds + 128 * 64);

  const int tid = threadIdx.x;
  const int w = tid >> 6, lane = tid & 63, g = lane >> 4, c = lane & 15;
  const int wr = w >> 1, wc = w & 1;
  const int bn = blockIdx.x & 7;   // N/128 = 8
  const int bm = blockIdx.x >> 3;  // M/128 = 64

  f32x4 acc[4][4] = {};

  const char* Ab = (const char*)(A + (size_t)bm * 128 * K);
  const char* Bb = (const char*)(Bw + (size_t)bn * 128 * K);

  for (int k0 = 0; k0 < K; k0 += 64) {
    __syncthreads();
    // stage 128x64 f16 tiles of A and B (reg-staged, XOR-swizzled rows of 128B)
#pragma unroll
    for (int j = 0; j < 4; ++j) {
      int lin = j * 4096 + tid * 16;
      int row = lin >> 7, colb = lin & 127;
      u32x4 va = *(const u32x4*)(Ab + (size_t)row * (K * 2) + k0 * 2 + colb);
      *(u32x4*)(ldsA + (lin ^ ((row & 7) << 4))) = va;
      u32x4 vb = *(const u32x4*)(Bb + (size_t)row * (K * 2) + k0 * 2 + colb);
      *(u32x4*)(ldsB + (lin ^ ((row & 7) << 4))) = vb;
    }
    __syncthreads();
#pragma unroll
    for (int kk = 0; kk < 2; ++kk) {
      h8 a[4], b[4];
#pragma unroll
      for (int mi = 0; mi < 4; ++mi) {
        int row = wr * 64 + mi * 16 + c;
        int off = row * 128 + kk * 64 + g * 16;
        a[mi] = *(const h8*)(ldsA + (off ^ ((row & 7) << 4)));
      }
#pragma unroll
      for (int ni = 0; ni < 4; ++ni) {
        int row = wc * 64 + ni * 16 + c;
        int off = row * 128 + kk * 64 + g * 16;
        b[ni] = *(const h8*)(ldsB + (off ^ ((row & 7) << 4)));
      }
#pragma unroll
      for (int mi = 0; mi < 4; ++mi)
#pragma unroll
        for (int ni = 0; ni < 4; ++ni)
          acc[mi][ni] = __builtin_amdgcn_mfma_f32_16x16x32_f16(a[mi], b[ni], acc[mi][ni], 0, 0, 0);
    }
  }

  // epilogue: C/D layout col=lane&15, row=(lane>>4)*4+r
#pragma unroll
  for (int mi = 0; mi < 4; ++mi)
#pragma unroll
    for (int ni = 0; ni < 4; ++ni)
#pragma unroll
      for (int r = 0; r < 4; ++r) {
        int m = bm * 128 + wr * 64 + mi * 16 + g * 4 + r;
        int n = bn * 128 + wc * 64 + ni * 16 + c;
        float v = acc[mi][ni][r] + bias[n];
        if (MODE == 0) {
          int bI = m >> 11, sI = m & 2047, hI = n >> 6, dkI = n & 63;
          ((_Float16*)Cout)[(((size_t)bI * H_ + hI) * S_ + sI) * DK_ + dkI] = (_Float16)v;
        } else {
          ((float*)Cout)[(size_t)m * D_ + n] = v;
        }
      }
}

// ---------------- causal flash attention ----------------
// Q,K: [B,H,S,DK] f16; Vt: [B,H,DK,S] f16; vals out: [B,S,H*DK] f16
__global__ __launch_bounds__(256) void attn_fwd(const _Float16* __restrict__ Q,
                                                const _Float16* __restrict__ K,
                                                const _Float16* __restrict__ Vt,
                                                _Float16* __restrict__ vals) {
  __shared__ unsigned short ldsK[64 * 64];
  __shared__ unsigned short ldsV[64 * 64];
  __shared__ unsigned short ldsP[4 * 32 * 64];
  char* pK = (char*)ldsK;
  char* pV = (char*)ldsV;
  char* pP = (char*)ldsP;

  const int tid = threadIdx.x;
  const int w = tid >> 6, lane = tid & 63, g = lane >> 4, c = lane & 15;
  const int bid = blockIdx.x;      // B*H*(S/128) = 1024
  const int bh = bid >> 4, qt = bid & 15;
  const int qbase = qt * 128;
  const int bI = bh >> 4, hI = bh & 15;

  const _Float16* Qb = Q + (size_t)bh * S_ * DK_;
  const char* Kb = (const char*)(K + (size_t)bh * S_ * DK_);
  const char* Vtb = (const char*)(Vt + (size_t)bh * DK_ * S_);

  // Q fragments hoisted to registers: wave owns 32 q-rows
  h8 qf[2][2];
#pragma unroll
  for (int mi = 0; mi < 2; ++mi)
#pragma unroll
    for (int kk = 0; kk < 2; ++kk) {
      int row = qbase + w * 32 + mi * 16 + c;
      qf[mi][kk] = *(const h8*)(Qb + (size_t)row * DK_ + kk * 32 + g * 8);
    }

  f32x4 o[2][4] = {};
  float mst[2][4], lst[2][4];
#pragma unroll
  for (int mi = 0; mi < 2; ++mi)
#pragma unroll
    for (int r = 0; r < 4; ++r) { mst[mi][r] = -1e30f; lst[mi][r] = 0.f; }

  const int ntile = (qbase >> 6) + 2;  // causal: only tiles with kv0 <= qmax
  for (int t = 0; t < ntile; ++t) {
    const int kv0 = t * 64;
    __syncthreads();  // prev iteration's LDS reads done
    {
      const char* Ks = Kb + (size_t)kv0 * (DK_ * 2);  // contiguous 8KB tile
#pragma unroll
      for (int j = 0; j < 2; ++j) {
        int lin = j * 4096 + tid * 16;
        int row = lin >> 7;
        u32x4 v = *(const u32x4*)(Ks + lin);
        *(u32x4*)(pK + (lin ^ ((row & 7) << 4))) = v;
      }
#pragma unroll
      for (int j = 0; j < 2; ++j) {
        int lin = j * 4096 + tid * 16;
        int dk = lin >> 7, colb = lin & 127;
        u32x4 v = *(const u32x4*)(Vtb + (size_t)dk * (S_ * 2) + (size_t)kv0 * 2 + colb);
        *(u32x4*)(pV + (lin ^ ((dk & 7) << 4))) = v;
      }
    }
    __syncthreads();  // staging visible

    // S = Q K^T  (A=Q rows, B=K rows; NT)
    f32x4 s[2][4] = {};
#pragma unroll
    for (int kk = 0; kk < 2; ++kk) {
      h8 kf[4];
#pragma unroll
      for (int ni = 0; ni < 4; ++ni) {
        int row = ni * 16 + c;
        int off = row * 128 + kk * 64 + g * 16;
        kf[ni] = *(const h8*)(pK + (off ^ ((row & 7) << 4)));
      }
#pragma unroll
      for (int mi = 0; mi < 2; ++mi)
#pragma unroll
        for (int ni = 0; ni < 4; ++ni)
          s[mi][ni] = __builtin_amdgcn_mfma_f32_16x16x32_f16(qf[mi][kk], kf[ni], s[mi][ni], 0, 0, 0);
    }

    // scale + causal mask (C/D layout: row=(g*4+r), col=c)
#pragma unroll
    for (int mi = 0; mi < 2; ++mi)
#pragma unroll
      for (int ni = 0; ni < 4; ++ni)
#pragma unroll
        for (int r = 0; r < 4; ++r) {
          int qrow = qbase + w * 32 + mi * 16 + g * 4 + r;
          int kcol = kv0 + ni * 16 + c;
          float v = s[mi][ni][r] * 0.125f;
          s[mi][ni][r] = (kcol <= qrow) ? v : -1e30f;
        }

    // online softmax; row values live in 16 lanes sharing g, cols across ni
#pragma unroll
    for (int mi = 0; mi < 2; ++mi)
#pragma unroll
      for (int r = 0; r < 4; ++r) {
        float tm = fmaxf(fmaxf(s[mi][0][r], s[mi][1][r]), fmaxf(s[mi][2][r], s[mi][3][r]));
        tm = fmaxf(tm, __shfl_xor(tm, 1));
        tm = fmaxf(tm, __shfl_xor(tm, 2));
        tm = fmaxf(tm, __shfl_xor(tm, 4));
        tm = fmaxf(tm, __shfl_xor(tm, 8));
        float mo = mst[mi][r];
        float mn = fmaxf(mo, tm);
        float al = __expf(mo - mn);
        float rs = 0.f;
#pragma unroll
        for (int ni = 0; ni < 4; ++ni) {
          float p = __expf(s[mi][ni][r] - mn);
          s[mi][ni][r] = p;
          rs += p;
        }
        rs += __shfl_xor(rs, 1);
        rs += __shfl_xor(rs, 2);
        rs += __shfl_xor(rs, 4);
        rs += __shfl_xor(rs, 8);
        mst[mi][r] = mn;
        lst[mi][r] = lst[mi][r] * al + rs;
#pragma unroll
        for (int nd = 0; nd < 4; ++nd) o[mi][nd][r] *= al;
      }

    // P -> f16 -> per-wave LDS (C-layout scatter write, swizzled)
#pragma unroll
    for (int mi = 0; mi < 2; ++mi)
#pragma unroll
      for (int ni = 0; ni < 4; ++ni)
#pragma unroll
        for (int r = 0; r < 4; ++r) {
          int prow = mi * 16 + g * 4 + r;
          int off = w * 4096 + prow * 128 + (ni * 16 + c) * 2;
          *(_Float16*)(pP + (off ^ ((prow & 7) << 4))) = (_Float16)s[mi][ni][r];
        }
    __syncthreads();  // P visible (within-wave RAW fence, all waves lockstep)

    // O += P V   (A=P rows, B=Vt rows)
#pragma unroll
    for (int kk = 0; kk < 2; ++kk) {
      h8 pf[2], vf[4];
#pragma unroll
      for (int mi = 0; mi < 2; ++mi) {
        int row = mi * 16 + c;
        int off = w * 4096 + row * 128 + kk * 64 + g * 16;
        pf[mi] = *(const h8*)(pP + (off ^ ((row & 7) << 4)));
      }
#pragma unroll
      for (int nd = 0; nd < 4; ++nd) {
        int row = nd * 16 + c;
        int off = row * 128 + kk * 64 + g * 16;
        vf[nd] = *(const h8*)(pV + (off ^ ((row & 7) << 4)));
      }
#pragma unroll
      for (int mi = 0; mi < 2; ++mi)
#pragma unroll
        for (int nd = 0; nd < 4; ++nd)
          o[mi][nd] = __builtin_amdgcn_mfma_f32_16x16x32_f16(pf[mi], vf[nd], o[mi][nd], 0, 0, 0);
    }
  }

  // epilogue: vals[b, s, h*64+dk] = O / l
#pragma unroll
  for (int mi = 0; mi < 2; ++mi)
#pragma unroll
    for (int nd = 0; nd < 4; ++nd)
#pragma unroll
      for (int r = 0; r < 4; ++r) {
        int qrow = qbase + w * 32 + mi * 16 + g * 4 + r;
        int col = hI * 64 + nd * 16 + c;
        float v = o[mi][nd][r] / lst[mi][r];
        vals[((size_t)bI * S_ + qrow) * D_ + col] = (_Float16)v;
      }
}

extern "C" void kernel_launch(void* const* d_in, const int* in_sizes, int n_in,
                              void* d_out, int out_size, void* d_ws, size_t ws_size,
                              hipStream_t stream) {
  const float* x  = (const float*)d_in[0];
  // d_in[1] = mask (fixed causal tril) — hardcoded in attn_fwd
  const float* Wq = (const float*)d_in[2];
  const float* bq = (const float*)d_in[3];
  const float* Wk = (const float*)d_in[4];
  const float* bk = (const float*)d_in[5];
  const float* Wv = (const float*)d_in[6];
  const float* bv = (const float*)d_in[7];
  const float* Wo = (const float*)d_in[8];
  const float* bo = (const float*)d_in[9];
  float* out = (float*)d_out;

  char* ws = (char*)d_ws;
  size_t off = 0;
  auto alloc = [&](size_t bytes) {
    char* p = ws + off;
    off += (bytes + 255) & ~(size_t)255;
    return p;
  };
  _Float16* xb   = (_Float16*)alloc((size_t)B_ * S_ * D_ * 2);
  _Float16* wqb  = (_Float16*)alloc((size_t)D_ * D_ * 2);
  _Float16* wkb  = (_Float16*)alloc((size_t)D_ * D_ * 2);
  _Float16* wvb  = (_Float16*)alloc((size_t)D_ * D_ * 2);
  _Float16* wob  = (_Float16*)alloc((size_t)D_ * D_ * 2);
  _Float16* Qw   = (_Float16*)alloc((size_t)B_ * H_ * S_ * DK_ * 2);
  _Float16* Kw   = (_Float16*)alloc((size_t)B_ * H_ * S_ * DK_ * 2);
  _Float16* Vw   = (_Float16*)alloc((size_t)B_ * H_ * S_ * DK_ * 2);
  _Float16* Vtw  = (_Float16*)alloc((size_t)B_ * H_ * S_ * DK_ * 2);
  _Float16* valw = (_Float16*)alloc((size_t)B_ * S_ * D_ * 2);

  const int nx8 = B_ * S_ * D_ / 8;
  conv_f16<<<(nx8 + 255) / 256, 256, 0, stream>>>(x, xb, nx8);
  const int nw8 = D_ * D_ / 8;
  conv_f16<<<(nw8 + 255) / 256, 256, 0, stream>>>(Wq, wqb, nw8);
  conv_f16<<<(nw8 + 255) / 256, 256, 0, stream>>>(Wk, wkb, nw8);
  conv_f16<<<(nw8 + 255) / 256, 256, 0, stream>>>(Wv, wvb, nw8);
  conv_f16<<<(nw8 + 255) / 256, 256, 0, stream>>>(Wo, wob, nw8);

  gemm_nt<0><<<512, 256, 0, stream>>>(xb, wqb, bq, Qw);
  gemm_nt<0><<<512, 256, 0, stream>>>(xb, wkb, bk, Kw);
  gemm_nt<0><<<512, 256, 0, stream>>>(xb, wvb, bv, Vw);

  transposeV<<<B_ * H_ * (S_ / 64), 256, 0, stream>>>(Vw, Vtw);

  attn_fwd<<<B_ * H_ * (S_ / 128), 256, 0, stream>>>(Qw, Kw, Vtw, valw);

  gemm_nt<1><<<512, 256, 0, stream>>>(valw, wob, bo, out);
}

// Round 2
// 273.841 us; speedup vs baseline: 1.3379x; 1.3379x over previous
//
#include <hip/hip_runtime.h>
#include <hip/hip_bf16.h>
#include <cstdint>

#define B_ 4
#define S_ 2048
#define D_ 1024
#define H_ 16
#define DK_ 64

typedef _Float16 h8 __attribute__((ext_vector_type(8)));
typedef _Float16 h4 __attribute__((ext_vector_type(4)));
typedef float f32x4 __attribute__((ext_vector_type(4)));
typedef unsigned int u32x4 __attribute__((ext_vector_type(4)));

// ---------------- f32 -> f16 convert (vectorized) ----------------
__global__ __launch_bounds__(256) void conv_f16(const float* __restrict__ src,
                                                _Float16* __restrict__ dst, int n8) {
  int i = blockIdx.x * 256 + threadIdx.x;
  if (i < n8) {
    int base = i * 8;
    h8 o;
#pragma unroll
    for (int j = 0; j < 8; ++j) o[j] = (_Float16)src[base + j];
    *(h8*)(dst + base) = o;
  }
}

// ---------------- V transpose: [B,H,S,DK] -> [B,H,DK,S] ----------------
__global__ __launch_bounds__(256) void transposeV(const _Float16* __restrict__ V,
                                                  _Float16* __restrict__ Vt) {
  __shared__ unsigned short t[64][72];  // +8 pad breaks bank conflicts
  const int bid = blockIdx.x;           // B*H*(S/64) = 2048
  const int bh = bid >> 5, st = bid & 31;
  const int s0 = st * 64;
  const unsigned short* Vb = (const unsigned short*)(V + (size_t)bh * S_ * DK_) + (size_t)s0 * DK_;
  unsigned short* Vtb = (unsigned short*)(Vt + (size_t)bh * DK_ * S_) + s0;
  const int tid = threadIdx.x;
#pragma unroll
  for (int i = 0; i < 16; ++i) {
    int idx = tid + i * 256;
    int r = idx >> 6, cc = idx & 63;
    t[r][cc] = Vb[r * 64 + cc];
  }
  __syncthreads();
#pragma unroll
  for (int i = 0; i < 16; ++i) {
    int idx = tid + i * 256;
    int dk = idx >> 6, sc = idx & 63;
    Vtb[(size_t)dk * S_ + sc] = t[sc][dk];
  }
}

// ---------------- NT GEMM: C[m,n] = sum_k A[m,k]*Bw[n,k] + bias[n] ----------------
template <int MODE>
__global__ __launch_bounds__(256) void gemm_nt(const _Float16* __restrict__ A,
                                               const _Float16* __restrict__ Bw,
                                               const float* __restrict__ bias,
                                               void* __restrict__ Cout) {
  constexpr int K = D_;  // 1024
  __shared__ unsigned short lds[2 * 128 * 64];
  char* ldsA = (char*)lds;
  char* ldsB = (char*)(lds + 128 * 64);

  const int tid = threadIdx.x;
  const int w = tid >> 6, lane = tid & 63, g = lane >> 4, c = lane & 15;
  const int wr = w >> 1, wc = w & 1;
  const int bn = blockIdx.x & 7;   // N/128 = 8
  const int bm = blockIdx.x >> 3;  // M/128 = 64

  f32x4 acc[4][4] = {};

  const char* Ab = (const char*)(A + (size_t)bm * 128 * K);
  const char* Bb = (const char*)(Bw + (size_t)bn * 128 * K);

  for (int k0 = 0; k0 < K; k0 += 64) {
    __syncthreads();
#pragma unroll
    for (int j = 0; j < 4; ++j) {
      int lin = j * 4096 + tid * 16;
      int row = lin >> 7, colb = lin & 127;
      u32x4 va = *(const u32x4*)(Ab + (size_t)row * (K * 2) + k0 * 2 + colb);
      *(u32x4*)(ldsA + (lin ^ ((row & 7) << 4))) = va;
      u32x4 vb = *(const u32x4*)(Bb + (size_t)row * (K * 2) + k0 * 2 + colb);
      *(u32x4*)(ldsB + (lin ^ ((row & 7) << 4))) = vb;
    }
    __syncthreads();
#pragma unroll
    for (int kk = 0; kk < 2; ++kk) {
      h8 a[4], b[4];
#pragma unroll
      for (int mi = 0; mi < 4; ++mi) {
        int row = wr * 64 + mi * 16 + c;
        int off = row * 128 + kk * 64 + g * 16;
        a[mi] = *(const h8*)(ldsA + (off ^ ((row & 7) << 4)));
      }
#pragma unroll
      for (int ni = 0; ni < 4; ++ni) {
        int row = wc * 64 + ni * 16 + c;
        int off = row * 128 + kk * 64 + g * 16;
        b[ni] = *(const h8*)(ldsB + (off ^ ((row & 7) << 4)));
      }
#pragma unroll
      for (int mi = 0; mi < 4; ++mi)
#pragma unroll
        for (int ni = 0; ni < 4; ++ni)
          acc[mi][ni] = __builtin_amdgcn_mfma_f32_16x16x32_f16(a[mi], b[ni], acc[mi][ni], 0, 0, 0);
    }
  }

#pragma unroll
  for (int mi = 0; mi < 4; ++mi)
#pragma unroll
    for (int ni = 0; ni < 4; ++ni)
#pragma unroll
      for (int r = 0; r < 4; ++r) {
        int m = bm * 128 + wr * 64 + mi * 16 + g * 4 + r;
        int n = bn * 128 + wc * 64 + ni * 16 + c;
        float v = acc[mi][ni][r] + bias[n];
        if (MODE == 0) {
          int bI = m >> 11, sI = m & 2047, hI = n >> 6, dkI = n & 63;
          ((_Float16*)Cout)[(((size_t)bI * H_ + hI) * S_ + sI) * DK_ + dkI] = (_Float16)v;
        } else {
          ((float*)Cout)[(size_t)m * D_ + n] = v;
        }
      }
}

// ---------------- causal flash attention (swapped-QK^T, paired q-tiles) ----
// Q,K: [B,H,S,DK] f16; Vt: [B,H,DK,S] f16; vals out: [B,S,H*DK] f16
// Block: 4 waves, each wave owns 16 q-rows -> QTILE=64. Block processes q-sub-
// tiles (pi, 31-pi): uniform 33 KV64-tiles of work -> no causal tail.
// S^T = mfma(K, Q): lane owns ONE q-column (q = lane&15) -> scalar m/l state,
// 2-shfl row reduce, b64-packed P writes.
__global__ __launch_bounds__(256) void attn_fwd(const _Float16* __restrict__ Q,
                                                const _Float16* __restrict__ K,
                                                const _Float16* __restrict__ Vt,
                                                _Float16* __restrict__ vals) {
  __shared__ unsigned short ldsK[64 * 64];
  __shared__ unsigned short ldsV[64 * 64];
  __shared__ unsigned short ldsP[4 * 16 * 64];
  char* pK = (char*)ldsK;
  char* pV = (char*)ldsV;
  char* pP = (char*)ldsP;

  const int tid = threadIdx.x;
  const int w = tid >> 6, lane = tid & 63, g = lane >> 4, c = lane & 15;
  const int bid = blockIdx.x;  // 64 bh * 16 pairs = 1024
  const int bh = bid >> 4, pi = bid & 15;
  const int bI = bh >> 4, hI = bh & 15;

  const char* Qb = (const char*)(Q + (size_t)bh * S_ * DK_);
  const char* Kb = (const char*)(K + (size_t)bh * S_ * DK_);
  const char* Vtb = (const char*)(Vt + (size_t)bh * DK_ * S_);

  // fold softmax scale and log2(e) into Q fragments
  const _Float16 qsc = (_Float16)(0.125f * 1.44269504f);

  for (int phase = 0; phase < 2; ++phase) {
    const int qsub = (phase == 0) ? pi : 31 - pi;
    const int qw0 = qsub * 64 + w * 16;  // this wave's first q row

    // Q fragment (B-operand): lane holds q-col c, k contiguous
    h8 qf[2];
#pragma unroll
    for (int kk = 0; kk < 2; ++kk) {
      h8 v = *(const h8*)(Qb + (size_t)(qw0 + c) * 128 + kk * 64 + g * 16);
#pragma unroll
      for (int j = 0; j < 8; ++j) v[j] *= qsc;
      qf[kk] = v;
    }

    f32x4 o[4] = {};
    float m_ = -1e30f, l_ = 0.f;

    const int ntile = qsub + 1;
    for (int t = 0; t < ntile; ++t) {
      const int kv0 = t * 64;
      __syncthreads();  // prior tile's LDS reads done
      {
        const char* Ks = Kb + (size_t)kv0 * 128;  // contiguous 8KB
#pragma unroll
        for (int j = 0; j < 2; ++j) {
          int lin = j * 4096 + tid * 16;
          int row = lin >> 7;
          u32x4 v = *(const u32x4*)(Ks + lin);
          *(u32x4*)(pK + (lin ^ ((row & 7) << 4))) = v;
        }
#pragma unroll
        for (int j = 0; j < 2; ++j) {
          int lin = j * 4096 + tid * 16;
          int dk = lin >> 7, colb = lin & 127;
          u32x4 v = *(const u32x4*)(Vtb + (size_t)dk * (S_ * 2) + (size_t)kv0 * 2 + colb);
          *(u32x4*)(pV + (lin ^ ((dk & 7) << 4))) = v;
        }
      }
      __syncthreads();  // staging visible

      // S^T = K Q^T : C layout -> col = q = c, row = kv = ni*16 + g*4 + r
      f32x4 s[4] = {};
#pragma unroll
      for (int kk = 0; kk < 2; ++kk) {
        h8 kf[4];
#pragma unroll
        for (int ni = 0; ni < 4; ++ni) {
          int row = ni * 16 + c;
          int off = row * 128 + kk * 64 + g * 16;
          kf[ni] = *(const h8*)(pK + (off ^ ((c & 7) << 4)));
        }
#pragma unroll
        for (int ni = 0; ni < 4; ++ni)
          s[ni] = __builtin_amdgcn_mfma_f32_16x16x32_f16(kf[ni], qf[kk], s[ni], 0, 0, 0);
      }

      // causal mask: only the diagonal tile needs it (wave-uniform branch)
      if (t == ntile - 1) {
#pragma unroll
        for (int ni = 0; ni < 4; ++ni)
#pragma unroll
          for (int r = 0; r < 4; ++r) {
            int kv = ni * 16 + g * 4 + r;        // kv within tile
            int q = w * 16 + c;                   // q within sub-tile (kv0 == qsub*64)
            if (kv > q) s[ni][r] = -1e30f;
          }
      }

      // online softmax (log2 domain; lane owns q = qw0 + c)
      float tm = s[0][0];
#pragma unroll
      for (int ni = 0; ni < 4; ++ni)
#pragma unroll
        for (int r = 0; r < 4; ++r) tm = fmaxf(tm, s[ni][r]);
      tm = fmaxf(tm, __shfl_xor(tm, 16));
      tm = fmaxf(tm, __shfl_xor(tm, 32));
      float mn = fmaxf(m_, tm);
      float al = __builtin_amdgcn_exp2f(m_ - mn);
      float rs = 0.f;
      float p[4][4];
#pragma unroll
      for (int ni = 0; ni < 4; ++ni)
#pragma unroll
        for (int r = 0; r < 4; ++r) {
          float e = __builtin_amdgcn_exp2f(s[ni][r] - mn);
          p[ni][r] = e;
          rs += e;
        }
      rs += __shfl_xor(rs, 16);
      rs += __shfl_xor(rs, 32);
      m_ = mn;
      l_ = l_ * al + rs;

      // O rescale: O rows are q = g*4+r -> fetch al(q) via variable shfl
#pragma unroll
      for (int r = 0; r < 4; ++r) {
        float alr = __shfl(al, g * 4 + r);
#pragma unroll
        for (int nd = 0; nd < 4; ++nd) o[nd][r] *= alr;
      }

      // P -> f16, packed b64 writes: P[q][kv] row-major per wave
#pragma unroll
      for (int ni = 0; ni < 4; ++ni) {
        h4 pk4 = {(_Float16)p[ni][0], (_Float16)p[ni][1], (_Float16)p[ni][2], (_Float16)p[ni][3]};
        int off = w * 2048 + c * 128 + ni * 32 + g * 8;
        *(h4*)(pP + (off ^ ((c & 7) << 4))) = pk4;
      }
      // per-wave P region; same-wave LDS RAW is ordered by lgkmcnt (no barrier)

      // O += P V : A = P rows (q = lane&15), B = V cols (dk = lane&15) from Vt rows
#pragma unroll
      for (int kk = 0; kk < 2; ++kk) {
        h8 pf, vf[4];
        {
          int off = w * 2048 + c * 128 + kk * 64 + g * 16;
          pf = *(const h8*)(pP + (off ^ ((c & 7) << 4)));
        }
#pragma unroll
        for (int nd = 0; nd < 4; ++nd) {
          int row = nd * 16 + c;
          int off = row * 128 + kk * 64 + g * 16;
          vf[nd] = *(const h8*)(pV + (off ^ ((c & 7) << 4)));
        }
#pragma unroll
        for (int nd = 0; nd < 4; ++nd)
          o[nd] = __builtin_amdgcn_mfma_f32_16x16x32_f16(pf, vf[nd], o[nd], 0, 0, 0);
      }
    }

    // epilogue: vals[b, q, h*64+dk] = O / l ; O rows q = g*4+r, cols dk = nd*16+c
#pragma unroll
    for (int r = 0; r < 4; ++r) {
      float lr = __shfl(l_, g * 4 + r);
      float inv = 1.0f / lr;
      int qrow = qsub * 64 + w * 16 + g * 4 + r;
#pragma unroll
      for (int nd = 0; nd < 4; ++nd) {
        int col = hI * 64 + nd * 16 + c;
        vals[((size_t)bI * S_ + qrow) * D_ + col] = (_Float16)(o[nd][r] * inv);
      }
    }
  }
}

extern "C" void kernel_launch(void* const* d_in, const int* in_sizes, int n_in,
                              void* d_out, int out_size, void* d_ws, size_t ws_size,
                              hipStream_t stream) {
  const float* x  = (const float*)d_in[0];
  // d_in[1] = mask (fixed causal tril) — hardcoded in attn_fwd
  const float* Wq = (const float*)d_in[2];
  const float* bq = (const float*)d_in[3];
  const float* Wk = (const float*)d_in[4];
  const float* bk = (const float*)d_in[5];
  const float* Wv = (const float*)d_in[6];
  const float* bv = (const float*)d_in[7];
  const float* Wo = (const float*)d_in[8];
  const float* bo = (const float*)d_in[9];
  float* out = (float*)d_out;

  char* ws = (char*)d_ws;
  size_t off = 0;
  auto alloc = [&](size_t bytes) {
    char* p = ws + off;
    off += (bytes + 255) & ~(size_t)255;
    return p;
  };
  _Float16* xb   = (_Float16*)alloc((size_t)B_ * S_ * D_ * 2);
  _Float16* wqb  = (_Float16*)alloc((size_t)D_ * D_ * 2);
  _Float16* wkb  = (_Float16*)alloc((size_t)D_ * D_ * 2);
  _Float16* wvb  = (_Float16*)alloc((size_t)D_ * D_ * 2);
  _Float16* wob  = (_Float16*)alloc((size_t)D_ * D_ * 2);
  _Float16* Qw   = (_Float16*)alloc((size_t)B_ * H_ * S_ * DK_ * 2);
  _Float16* Kw   = (_Float16*)alloc((size_t)B_ * H_ * S_ * DK_ * 2);
  _Float16* Vw   = (_Float16*)alloc((size_t)B_ * H_ * S_ * DK_ * 2);
  _Float16* Vtw  = (_Float16*)alloc((size_t)B_ * H_ * S_ * DK_ * 2);
  _Float16* valw = (_Float16*)alloc((size_t)B_ * S_ * D_ * 2);

  const int nx8 = B_ * S_ * D_ / 8;
  conv_f16<<<(nx8 + 255) / 256, 256, 0, stream>>>(x, xb, nx8);
  const int nw8 = D_ * D_ / 8;
  conv_f16<<<(nw8 + 255) / 256, 256, 0, stream>>>(Wq, wqb, nw8);
  conv_f16<<<(nw8 + 255) / 256, 256, 0, stream>>>(Wk, wkb, nw8);
  conv_f16<<<(nw8 + 255) / 256, 256, 0, stream>>>(Wv, wvb, nw8);
  conv_f16<<<(nw8 + 255) / 256, 256, 0, stream>>>(Wo, wob, nw8);

  gemm_nt<0><<<512, 256, 0, stream>>>(xb, wqb, bq, Qw);
  gemm_nt<0><<<512, 256, 0, stream>>>(xb, wkb, bk, Kw);
  gemm_nt<0><<<512, 256, 0, stream>>>(xb, wvb, bv, Vw);

  transposeV<<<B_ * H_ * (S_ / 64), 256, 0, stream>>>(Vw, Vtw);

  attn_fwd<<<B_ * H_ * (S_ / 128), 256, 0, stream>>>(Qw, Kw, Vtw, valw);

  gemm_nt<1><<<512, 256, 0, stream>>>(valw, wob, bo, out);
}

// Round 3
// 202.888 us; speedup vs baseline: 1.8057x; 1.3497x over previous
//
#include <hip/hip_runtime.h>
#include <hip/hip_bf16.h>
#include <cstdint>

#define B_ 4
#define S_ 2048
#define D_ 1024
#define H_ 16
#define DK_ 64

typedef _Float16 h8 __attribute__((ext_vector_type(8)));
typedef _Float16 h4 __attribute__((ext_vector_type(4)));
typedef float f32x4 __attribute__((ext_vector_type(4)));
typedef unsigned int u32x4 __attribute__((ext_vector_type(4)));

// async global->LDS, 16B per lane. LDS dest = wave-uniform base + lane*16.
__device__ __forceinline__ void gload16(const void* src, void* lds) {
  __builtin_amdgcn_global_load_lds((const __attribute__((address_space(1))) void*)src,
                                   (__attribute__((address_space(3))) void*)lds, 16, 0, 0);
}

// ---------------- x: f32 -> f16 (vectorized) ----------------
__global__ __launch_bounds__(256) void conv_f16(const float* __restrict__ src,
                                                _Float16* __restrict__ dst, int n8) {
  int i = blockIdx.x * 256 + threadIdx.x;
  if (i < n8) {
    int base = i * 8;
    h8 o;
#pragma unroll
    for (int j = 0; j < 8; ++j) o[j] = (_Float16)src[base + j];
    *(h8*)(dst + base) = o;
  }
}

// ---------------- weights: convert + concat QKV (and bias concat) ----------
__global__ __launch_bounds__(256) void conv_weights(
    const float* __restrict__ Wq, const float* __restrict__ Wk,
    const float* __restrict__ Wv, const float* __restrict__ Wo,
    const float* __restrict__ bq, const float* __restrict__ bk,
    const float* __restrict__ bv,
    _Float16* __restrict__ wqkv, _Float16* __restrict__ wo,
    float* __restrict__ bqkv) {
  int i = blockIdx.x * 256 + threadIdx.x;  // 2048 blocks -> 524288 threads, 8 f32 each
  int seg = i >> 17, r = i & 131071;
  const float* src = seg == 0 ? Wq : seg == 1 ? Wk : seg == 2 ? Wv : Wo;
  int base = r * 8;
  h8 o;
#pragma unroll
  for (int j = 0; j < 8; ++j) o[j] = (_Float16)src[base + j];
  if (seg < 3)
    *(h8*)(wqkv + (size_t)seg * 1048576 + base) = o;
  else
    *(h8*)(wo + base) = o;
  if (i < 768) {  // bias concat: 3 x 1024 f32
    int bsel = i >> 8, k = (i & 255) * 4;
    const float* bs = bsel == 0 ? bq : bsel == 1 ? bk : bv;
    float4 v = *(const float4*)(bs + k);
    *(float4*)(bqkv + bsel * 1024 + k) = v;
  }
}

// ---------------- V transpose: [B,H,S,DK] -> [B,H,DK,S] ----------------
__global__ __launch_bounds__(256) void transposeV(const _Float16* __restrict__ V,
                                                  _Float16* __restrict__ Vt) {
  __shared__ unsigned short t[64][72];
  const int bid = blockIdx.x;  // B*H*(S/64) = 2048
  const int bh = bid >> 5, st = bid & 31;
  const int s0 = st * 64;
  const unsigned short* Vb = (const unsigned short*)(V + (size_t)bh * S_ * DK_) + (size_t)s0 * DK_;
  unsigned short* Vtb = (unsigned short*)(Vt + (size_t)bh * DK_ * S_) + s0;
  const int tid = threadIdx.x;
#pragma unroll
  for (int i = 0; i < 16; ++i) {
    int idx = tid + i * 256;
    int r = idx >> 6, cc = idx & 63;
    t[r][cc] = Vb[r * 64 + cc];
  }
  __syncthreads();
#pragma unroll
  for (int i = 0; i < 16; ++i) {
    int idx = tid + i * 256;
    int dk = idx >> 6, sc = idx & 63;
    Vtb[(size_t)dk * S_ + sc] = t[sc][dk];
  }
}

// ---------------- NT GEMM: C[m,n] = sum_k A[m,k]*Bw[n,k] + bias[n] -----------
// MODE 0: N=3072 fused QKV, f16 out routed to [3][B,H,S,DK] at Cout.
// MODE 1: N=1024, f32 out [M][1024].
// Staging: global_load_lds w16, linear LDS dest, inverse-swizzled source,
// XOR-swizzled reads (rule #21).
template <int MODE>
__global__ __launch_bounds__(256) void gemm_nt(const _Float16* __restrict__ A,
                                               const _Float16* __restrict__ Bw,
                                               const float* __restrict__ bias,
                                               void* __restrict__ Cout) {
  constexpr int K = D_;  // 1024
  __shared__ unsigned short lds[2 * 128 * 64];
  char* ldsA = (char*)lds;
  char* ldsB = (char*)(lds + 128 * 64);

  const int tid = threadIdx.x;
  const int w = tid >> 6, lane = tid & 63, g = lane >> 4, c = lane & 15;
  const int wr = w >> 1, wc = w & 1;
  const int bn = blockIdx.x;  // N/128
  const int bm = blockIdx.y;  // M/128 = 64

  f32x4 acc[4][4] = {};

  // staging invariants: pass j covers lin = j*4096 + tid*16 ; row = lin>>7
  const int srow = tid >> 3;                                  // row within 32-row chunk
  const int scolsw = ((tid & 7) * 16) ^ ((srow & 7) << 4);    // inverse-swizzled col
  const char* Ab = (const char*)(A + (size_t)bm * 128 * K);
  const char* Bb = (const char*)(Bw + (size_t)bn * 128 * K);
  const char* Asrc[4];
  const char* Bsrc[4];
#pragma unroll
  for (int j = 0; j < 4; ++j) {
    int row = j * 32 + srow;
    Asrc[j] = Ab + (size_t)row * (K * 2) + scolsw;
    Bsrc[j] = Bb + (size_t)row * (K * 2) + scolsw;
  }
  char* dstA = ldsA + w * 1024;
  char* dstB = ldsB + w * 1024;

  for (int k0 = 0; k0 < K; k0 += 64) {
    __syncthreads();  // prev compute's LDS reads done
#pragma unroll
    for (int j = 0; j < 4; ++j) {
      gload16(Asrc[j] + k0 * 2, dstA + j * 4096);
      gload16(Bsrc[j] + k0 * 2, dstB + j * 4096);
    }
    __syncthreads();  // compiler drains vmcnt before barrier -> tiles ready
#pragma unroll
    for (int kk = 0; kk < 2; ++kk) {
      h8 a[4], b[4];
#pragma unroll
      for (int mi = 0; mi < 4; ++mi) {
        int row = wr * 64 + mi * 16 + c;
        int off = row * 128 + kk * 64 + g * 16;
        a[mi] = *(const h8*)(ldsA + (off ^ ((row & 7) << 4)));
      }
#pragma unroll
      for (int ni = 0; ni < 4; ++ni) {
        int row = wc * 64 + ni * 16 + c;
        int off = row * 128 + kk * 64 + g * 16;
        b[ni] = *(const h8*)(ldsB + (off ^ ((row & 7) << 4)));
      }
#pragma unroll
      for (int mi = 0; mi < 4; ++mi)
#pragma unroll
        for (int ni = 0; ni < 4; ++ni)
          acc[mi][ni] = __builtin_amdgcn_mfma_f32_16x16x32_f16(a[mi], b[ni], acc[mi][ni], 0, 0, 0);
    }
  }

#pragma unroll
  for (int mi = 0; mi < 4; ++mi)
#pragma unroll
    for (int ni = 0; ni < 4; ++ni)
#pragma unroll
      for (int r = 0; r < 4; ++r) {
        int m = bm * 128 + wr * 64 + mi * 16 + g * 4 + r;
        int n = bn * 128 + wc * 64 + ni * 16 + c;
        float v = acc[mi][ni][r] + bias[n];
        if (MODE == 0) {
          int which = n >> 10, nn = n & 1023;
          int bI = m >> 11, sI = m & 2047, hI = nn >> 6, dkI = nn & 63;
          ((_Float16*)Cout)[(size_t)which * 8388608 +
                            (((size_t)bI * H_ + hI) * S_ + sI) * DK_ + dkI] = (_Float16)v;
        } else {
          ((float*)Cout)[(size_t)m * D_ + n] = v;
        }
      }
}

// ---------------- causal flash attention ------------------------------------
// Swapped QK^T (lane owns one q-col), paired q-subtiles (uniform work),
// double-buffered K/V via global_load_lds, defer-max rescale (T13).
__global__ __launch_bounds__(256) void attn_fwd(const _Float16* __restrict__ Q,
                                                const _Float16* __restrict__ K,
                                                const _Float16* __restrict__ Vt,
                                                _Float16* __restrict__ vals) {
  __shared__ unsigned short ldsK[2 * 64 * 64];  // 2 x 8KB
  __shared__ unsigned short ldsV[2 * 64 * 64];  // 2 x 8KB
  __shared__ unsigned short ldsP[4 * 16 * 64];  // 8KB
  char* pK = (char*)ldsK;
  char* pV = (char*)ldsV;
  char* pP = (char*)ldsP;

  const int tid = threadIdx.x;
  const int w = tid >> 6, lane = tid & 63, g = lane >> 4, c = lane & 15;
  const int bid = blockIdx.x;  // 64 bh * 16 pairs
  const int bh = bid >> 4, pi = bid & 15;
  const int bI = bh >> 4, hI = bh & 15;

  const char* Qb = (const char*)(Q + (size_t)bh * S_ * DK_);
  const char* Kb = (const char*)(K + (size_t)bh * S_ * DK_);
  const char* Vtb = (const char*)(Vt + (size_t)bh * DK_ * S_);

  // staging invariants: pass j covers lin = j*4096 + tid*16 ; row = lin>>7
  const int srow = tid >> 3;
  const int scol = (tid & 7) * 16;
  int offK[2], offV[2];
#pragma unroll
  for (int j = 0; j < 2; ++j) {
    int row = j * 32 + srow;
    int colsw = scol ^ ((row & 7) << 4);
    offK[j] = row * 128 + colsw;        // K tile contiguous [64][128B]
    offV[j] = row * 4096 + colsw;       // Vt row stride = S*2 = 4096B
  }
  char* dstK = pK + w * 1024;
  char* dstV = pV + w * 1024;

  auto stage = [&](int buf, int kv0) {
#pragma unroll
    for (int j = 0; j < 2; ++j) {
      gload16(Kb + (size_t)kv0 * 128 + offK[j], dstK + buf * 8192 + j * 4096);
      gload16(Vtb + (size_t)kv0 * 2 + offV[j], dstV + buf * 8192 + j * 4096);
    }
  };

  const _Float16 qsc = (_Float16)(0.125f * 1.44269504f);  // scale * log2(e)

  for (int phase = 0; phase < 2; ++phase) {
    const int qsub = (phase == 0) ? pi : 31 - pi;
    const int qw0 = qsub * 64 + w * 16;

    h8 qf[2];
#pragma unroll
    for (int kk = 0; kk < 2; ++kk) {
      h8 v = *(const h8*)(Qb + (size_t)(qw0 + c) * 128 + kk * 64 + g * 16);
#pragma unroll
      for (int j = 0; j < 8; ++j) v[j] *= qsc;
      qf[kk] = v;
    }

    f32x4 o[4] = {};
    float m_ = -1e30f, l_ = 0.f;

    const int ntile = qsub + 1;
    stage(0, 0);
    __syncthreads();  // buf0 ready (vmcnt drained at barrier)

    for (int t = 0; t < ntile; ++t) {
      const int cur = t & 1;
      if (t + 1 < ntile) stage(cur ^ 1, (t + 1) * 64);  // prefetch under compute
      const char* bK = pK + cur * 8192;
      const char* bV = pV + cur * 8192;

      // S^T = K Q^T : col = q = c, row = kv = ni*16 + g*4 + r
      f32x4 s[4] = {};
#pragma unroll
      for (int kk = 0; kk < 2; ++kk) {
        h8 kf[4];
#pragma unroll
        for (int ni = 0; ni < 4; ++ni) {
          int row = ni * 16 + c;
          int off = row * 128 + kk * 64 + g * 16;
          kf[ni] = *(const h8*)(bK + (off ^ ((c & 7) << 4)));
        }
#pragma unroll
        for (int ni = 0; ni < 4; ++ni)
          s[ni] = __builtin_amdgcn_mfma_f32_16x16x32_f16(kf[ni], qf[kk], s[ni], 0, 0, 0);
      }

      // causal mask: diagonal tile only (wave-uniform branch)
      if (t == ntile - 1) {
#pragma unroll
        for (int ni = 0; ni < 4; ++ni)
#pragma unroll
          for (int r = 0; r < 4; ++r) {
            int kv = ni * 16 + g * 4 + r;
            int q = w * 16 + c;
            if (kv > q) s[ni][r] = -1e30f;
          }
      }

      // online softmax, log2 domain, lane owns q = qw0 + c
      float tm = s[0][0];
#pragma unroll
      for (int ni = 0; ni < 4; ++ni)
#pragma unroll
        for (int r = 0; r < 4; ++r) tm = fmaxf(tm, s[ni][r]);
      tm = fmaxf(tm, __shfl_xor(tm, 16));
      tm = fmaxf(tm, __shfl_xor(tm, 32));

      // defer-max (T13): skip O-rescale while max grows < 8 (log2 units)
      const bool noresc = __all(tm <= m_ + 8.f);
      const float mn = noresc ? m_ : fmaxf(m_, tm);

      float rs = 0.f;
      float p[4][4];
#pragma unroll
      for (int ni = 0; ni < 4; ++ni)
#pragma unroll
        for (int r = 0; r < 4; ++r) {
          float e = __builtin_amdgcn_exp2f(s[ni][r] - mn);
          p[ni][r] = e;
          rs += e;
        }
      rs += __shfl_xor(rs, 16);
      rs += __shfl_xor(rs, 32);

      if (noresc) {
        l_ += rs;
      } else {
        float al = __builtin_amdgcn_exp2f(m_ - mn);
        l_ = l_ * al + rs;
        m_ = mn;
#pragma unroll
        for (int r = 0; r < 4; ++r) {
          float alr = __shfl(al, g * 4 + r);
#pragma unroll
          for (int nd = 0; nd < 4; ++nd) o[nd][r] *= alr;
        }
      }

      // P -> f16, packed b64 writes: per-wave P[q][kv]
#pragma unroll
      for (int ni = 0; ni < 4; ++ni) {
        h4 pk4 = {(_Float16)p[ni][0], (_Float16)p[ni][1], (_Float16)p[ni][2], (_Float16)p[ni][3]};
        int off = w * 2048 + c * 128 + ni * 32 + g * 8;
        *(h4*)(pP + (off ^ ((c & 7) << 4))) = pk4;
      }
      // same-wave LDS RAW ordered by lgkmcnt; no barrier needed

      // O += P V
#pragma unroll
      for (int kk = 0; kk < 2; ++kk) {
        h8 pf, vf[4];
        {
          int off = w * 2048 + c * 128 + kk * 64 + g * 16;
          pf = *(const h8*)(pP + (off ^ ((c & 7) << 4)));
        }
#pragma unroll
        for (int nd = 0; nd < 4; ++nd) {
          int row = nd * 16 + c;
          int off = row * 128 + kk * 64 + g * 16;
          vf[nd] = *(const h8*)(bV + (off ^ ((c & 7) << 4)));
        }
#pragma unroll
        for (int nd = 0; nd < 4; ++nd)
          o[nd] = __builtin_amdgcn_mfma_f32_16x16x32_f16(pf, vf[nd], o[nd], 0, 0, 0);
      }

      __syncthreads();  // stage(t+1) drained; all reads of buf[cur] done
    }

    // epilogue: vals[b, q, h*64+dk] = O / l
#pragma unroll
    for (int r = 0; r < 4; ++r) {
      float lr = __shfl(l_, g * 4 + r);
      float inv = 1.0f / lr;
      int qrow = qsub * 64 + w * 16 + g * 4 + r;
#pragma unroll
      for (int nd = 0; nd < 4; ++nd) {
        int col = hI * 64 + nd * 16 + c;
        vals[((size_t)bI * S_ + qrow) * D_ + col] = (_Float16)(o[nd][r] * inv);
      }
    }
  }
}

extern "C" void kernel_launch(void* const* d_in, const int* in_sizes, int n_in,
                              void* d_out, int out_size, void* d_ws, size_t ws_size,
                              hipStream_t stream) {
  const float* x  = (const float*)d_in[0];
  // d_in[1] = mask (fixed causal tril) — hardcoded in attn_fwd
  const float* Wq = (const float*)d_in[2];
  const float* bq = (const float*)d_in[3];
  const float* Wk = (const float*)d_in[4];
  const float* bk = (const float*)d_in[5];
  const float* Wv = (const float*)d_in[6];
  const float* bv = (const float*)d_in[7];
  const float* Wo = (const float*)d_in[8];
  const float* bo = (const float*)d_in[9];
  float* out = (float*)d_out;

  char* ws = (char*)d_ws;
  size_t off = 0;
  auto alloc = [&](size_t bytes) {
    char* p = ws + off;
    off += (bytes + 255) & ~(size_t)255;
    return p;
  };
  _Float16* xb   = (_Float16*)alloc((size_t)B_ * S_ * D_ * 2);          // 16MB
  _Float16* wqkv = (_Float16*)alloc((size_t)3 * D_ * D_ * 2);           // 6MB
  _Float16* wob  = (_Float16*)alloc((size_t)D_ * D_ * 2);               // 2MB
  float*    bqkv = (float*)alloc((size_t)3 * D_ * 4);                   // 12KB
  _Float16* qkvw = (_Float16*)alloc((size_t)3 * B_ * H_ * S_ * DK_ * 2);// 48MB
  _Float16* Vtw  = (_Float16*)alloc((size_t)B_ * H_ * S_ * DK_ * 2);    // 16MB
  _Float16* valw = (_Float16*)alloc((size_t)B_ * S_ * D_ * 2);          // 16MB

  const int nx8 = B_ * S_ * D_ / 8;
  conv_f16<<<(nx8 + 255) / 256, 256, 0, stream>>>(x, xb, nx8);
  conv_weights<<<2048, 256, 0, stream>>>(Wq, Wk, Wv, Wo, bq, bk, bv, wqkv, wob, bqkv);

  gemm_nt<0><<<dim3(24, 64), 256, 0, stream>>>(xb, wqkv, bqkv, qkvw);

  transposeV<<<B_ * H_ * (S_ / 64), 256, 0, stream>>>(qkvw + (size_t)2 * 8388608, Vtw);

  attn_fwd<<<1024, 256, 0, stream>>>(qkvw, qkvw + (size_t)8388608, Vtw, valw);

  gemm_nt<1><<<dim3(8, 64), 256, 0, stream>>>(valw, wob, bo, out);
}

// Round 5
// 194.669 us; speedup vs baseline: 1.8820x; 1.0422x over previous
//
#include <hip/hip_runtime.h>
#include <hip/hip_bf16.h>
#include <cstdint>

#define B_ 4
#define S_ 2048
#define D_ 1024
#define H_ 16
#define DK_ 64

typedef _Float16 h8 __attribute__((ext_vector_type(8)));
typedef _Float16 h4 __attribute__((ext_vector_type(4)));
typedef _Float16 h2 __attribute__((ext_vector_type(2)));
typedef float f32x4 __attribute__((ext_vector_type(4)));
typedef unsigned int u32x4 __attribute__((ext_vector_type(4)));

// async global->LDS, 16B per lane. LDS dest = wave-uniform base + lane*16.
__device__ __forceinline__ void gload16(const void* src, void* lds) {
  __builtin_amdgcn_global_load_lds((const __attribute__((address_space(1))) void*)src,
                                   (__attribute__((address_space(3))) void*)lds, 16, 0, 0);
}

// ---------------- x: f32 -> f16 (vectorized) ----------------
__global__ __launch_bounds__(256) void conv_f16(const float* __restrict__ src,
                                                _Float16* __restrict__ dst, int n8) {
  int i = blockIdx.x * 256 + threadIdx.x;
  if (i < n8) {
    int base = i * 8;
    h8 o;
#pragma unroll
    for (int j = 0; j < 8; ++j) o[j] = (_Float16)src[base + j];
    *(h8*)(dst + base) = o;
  }
}

// ---------------- weights: convert + concat QKV (and bias concat) ----------
__global__ __launch_bounds__(256) void conv_weights(
    const float* __restrict__ Wq, const float* __restrict__ Wk,
    const float* __restrict__ Wv, const float* __restrict__ Wo,
    const float* __restrict__ bq, const float* __restrict__ bk,
    const float* __restrict__ bv,
    _Float16* __restrict__ wqkv, _Float16* __restrict__ wo,
    float* __restrict__ bqkv) {
  int i = blockIdx.x * 256 + threadIdx.x;  // 2048 blocks, 8 f32 each
  int seg = i >> 17, r = i & 131071;
  const float* src = seg == 0 ? Wq : seg == 1 ? Wk : seg == 2 ? Wv : Wo;
  int base = r * 8;
  h8 o;
#pragma unroll
  for (int j = 0; j < 8; ++j) o[j] = (_Float16)src[base + j];
  if (seg < 3)
    *(h8*)(wqkv + (size_t)seg * 1048576 + base) = o;
  else
    *(h8*)(wo + base) = o;
  if (i < 768) {  // bias concat: 3 x 1024 f32
    int bsel = i >> 8, k = (i & 255) * 4;
    const float* bs = bsel == 0 ? bq : bsel == 1 ? bk : bv;
    float4 v = *(const float4*)(bs + k);
    *(float4*)(bqkv + bsel * 1024 + k) = v;
  }
}

// ---------------- NT GEMM: C[m,n] = sum_k A[m,k]*Bw[n,k] + bias[n] -----------
// MODE 0: N=3072 fused QKV; Q,K segments -> [2][B,H,S,DK] f16 at Cout;
//         V segment written TRANSPOSED -> Vt [B,H,DK,S] f16 (h4 packed stores).
// MODE 1: N=1024, f32 out [M][1024].
template <int MODE>
__global__ __launch_bounds__(256) void gemm_nt(const _Float16* __restrict__ A,
                                               const _Float16* __restrict__ Bw,
                                               const float* __restrict__ bias,
                                               void* __restrict__ Cout,
                                               _Float16* __restrict__ Vt) {
  constexpr int K = D_;  // 1024
  __shared__ unsigned short lds[2 * 128 * 64];
  char* ldsA = (char*)lds;
  char* ldsB = (char*)(lds + 128 * 64);

  const int tid = threadIdx.x;
  const int w = tid >> 6, lane = tid & 63, g = lane >> 4, c = lane & 15;
  const int wr = w >> 1, wc = w & 1;
  const int bn = blockIdx.x;  // N/128
  const int bm = blockIdx.y;  // M/128 = 64

  f32x4 acc[4][4] = {};

  const int srow = tid >> 3;
  const int scolsw = ((tid & 7) * 16) ^ ((srow & 7) << 4);  // inverse-swizzled src col
  const char* Ab = (const char*)(A + (size_t)bm * 128 * K);
  const char* Bb = (const char*)(Bw + (size_t)bn * 128 * K);
  const char* Asrc[4];
  const char* Bsrc[4];
#pragma unroll
  for (int j = 0; j < 4; ++j) {
    int row = j * 32 + srow;
    Asrc[j] = Ab + (size_t)row * (K * 2) + scolsw;
    Bsrc[j] = Bb + (size_t)row * (K * 2) + scolsw;
  }
  char* dstA = ldsA + w * 1024;
  char* dstB = ldsB + w * 1024;

  for (int k0 = 0; k0 < K; k0 += 64) {
    __syncthreads();
#pragma unroll
    for (int j = 0; j < 4; ++j) {
      gload16(Asrc[j] + k0 * 2, dstA + j * 4096);
      gload16(Bsrc[j] + k0 * 2, dstB + j * 4096);
    }
    __syncthreads();
#pragma unroll
    for (int kk = 0; kk < 2; ++kk) {
      h8 a[4], b[4];
#pragma unroll
      for (int mi = 0; mi < 4; ++mi) {
        int row = wr * 64 + mi * 16 + c;
        int off = row * 128 + kk * 64 + g * 16;
        a[mi] = *(const h8*)(ldsA + (off ^ ((row & 7) << 4)));
      }
#pragma unroll
      for (int ni = 0; ni < 4; ++ni) {
        int row = wc * 64 + ni * 16 + c;
        int off = row * 128 + kk * 64 + g * 16;
        b[ni] = *(const h8*)(ldsB + (off ^ ((row & 7) << 4)));
      }
      __builtin_amdgcn_s_setprio(1);
#pragma unroll
      for (int mi = 0; mi < 4; ++mi)
#pragma unroll
        for (int ni = 0; ni < 4; ++ni)
          acc[mi][ni] = __builtin_amdgcn_mfma_f32_16x16x32_f16(a[mi], b[ni], acc[mi][ni], 0, 0, 0);
      __builtin_amdgcn_s_setprio(0);
    }
  }

  if (MODE == 0 && bn >= 16) {
    // V segment -> Vt [bh][dk][s]: 4 consecutive s rows pack into one h4 store
#pragma unroll
    for (int mi = 0; mi < 4; ++mi)
#pragma unroll
      for (int ni = 0; ni < 4; ++ni) {
        int m0 = bm * 128 + wr * 64 + mi * 16 + g * 4;
        int n = bn * 128 + wc * 64 + ni * 16 + c;
        float bb = bias[n];
        h4 v4;
#pragma unroll
        for (int r = 0; r < 4; ++r) v4[r] = (_Float16)(acc[mi][ni][r] + bb);
        int bI = m0 >> 11, sI = m0 & 2047;
        int dk = n & 63, hh = (n >> 6) & 15;
        *(h4*)(Vt + (((size_t)(bI * 16 + hh) * 64 + dk) * 2048 + sI)) = v4;
      }
  } else {
#pragma unroll
    for (int mi = 0; mi < 4; ++mi)
#pragma unroll
      for (int ni = 0; ni < 4; ++ni)
#pragma unroll
        for (int r = 0; r < 4; ++r) {
          int m = bm * 128 + wr * 64 + mi * 16 + g * 4 + r;
          int n = bn * 128 + wc * 64 + ni * 16 + c;
          float v = acc[mi][ni][r] + bias[n];
          if (MODE == 0) {
            int which = n >> 10, nn = n & 1023;
            int bI = m >> 11, sI = m & 2047, hI = nn >> 6, dkI = nn & 63;
            ((_Float16*)Cout)[(size_t)which * 8388608 +
                              (((size_t)bI * H_ + hI) * S_ + sI) * DK_ + dkI] = (_Float16)v;
          } else {
            ((float*)Cout)[(size_t)m * D_ + n] = v;
          }
        }
  }
}

// ---------------- causal flash attention ------------------------------------
// Merged paired q-subtiles (q0=pi, q1=31-pi) share ONE KV loop: each staged
// K/V tile feeds both groups' QK^T and PV (2x MFMA per stage/barrier).
// Swapped QK^T (lane owns q-col), per-lane deferred l-reduce, vcmp-only
// defer-max trigger (no shfl in common path), cvt_pkrtz P pack, T5 setprio.
__global__ __launch_bounds__(256, 4) void attn_fwd(const _Float16* __restrict__ Q,
                                                   const _Float16* __restrict__ K,
                                                   const _Float16* __restrict__ Vt,
                                                   _Float16* __restrict__ vals) {
  __shared__ unsigned short ldsK[2 * 64 * 64];  // 16KB
  __shared__ unsigned short ldsV[2 * 64 * 64];  // 16KB
  __shared__ unsigned short ldsP[4 * 16 * 64];  // 8KB, reused by both groups
  char* pK = (char*)ldsK;
  char* pV = (char*)ldsV;
  char* pP = (char*)ldsP;

  const int tid = threadIdx.x;
  const int w = tid >> 6, lane = tid & 63, g = lane >> 4, c = lane & 15;
  const int bid = blockIdx.x;
  const int pi = bid >> 6;   // 0..15; pi=0 (longest, 32 tiles) dispatched first
  const int bh = bid & 63;   // consecutive bids -> consecutive bh -> stable bh->XCD
  const int bI = bh >> 4, hI = bh & 15;
  const int q0 = pi, q1 = 31 - pi;

  const char* Qb = (const char*)(Q + (size_t)bh * S_ * DK_);
  const char* Kb = (const char*)(K + (size_t)bh * S_ * DK_);
  const char* Vtb = (const char*)(Vt + (size_t)bh * DK_ * S_);

  const int srow = tid >> 3;
  const int scol = (tid & 7) * 16;
  int offK[2], offV[2];
#pragma unroll
  for (int j = 0; j < 2; ++j) {
    int row = j * 32 + srow;
    int colsw = scol ^ ((row & 7) << 4);
    offK[j] = row * 128 + colsw;   // K tile contiguous [64][128B]
    offV[j] = row * 4096 + colsw;  // Vt row stride = S*2 = 4096B
  }
  char* dstK = pK + w * 1024;
  char* dstV = pV + w * 1024;

  auto stage = [&](int buf, int kv0) {
#pragma unroll
    for (int j = 0; j < 2; ++j) {
      gload16(Kb + (size_t)kv0 * 128 + offK[j], dstK + buf * 8192 + j * 4096);
      gload16(Vtb + (size_t)kv0 * 2 + offV[j], dstV + buf * 8192 + j * 4096);
    }
  };

  const _Float16 qsc = (_Float16)(0.125f * 1.44269504f);  // scale * log2(e)
  h8 qf[2][2];
#pragma unroll
  for (int gi = 0; gi < 2; ++gi) {
    int qsub = gi ? q1 : q0;
    int qr = qsub * 64 + w * 16 + c;
#pragma unroll
    for (int kk = 0; kk < 2; ++kk) {
      h8 v = *(const h8*)(Qb + (size_t)qr * 128 + kk * 64 + g * 16);
#pragma unroll
      for (int j = 0; j < 8; ++j) v[j] *= qsc;
      qf[gi][kk] = v;
    }
  }

  f32x4 o0[4] = {}, o1[4] = {};
  float m0v = -1e30f, l0v = 0.f, m1v = -1e30f, l1v = 0.f;

  const int nt = q1 + 1;
  stage(0, 0);
  __syncthreads();

  const int sw = (c & 7) << 4;

  for (int t = 0; t < nt; ++t) {
    const int cur = t & 1;
    if (t + 1 < nt) stage(cur ^ 1, (t + 1) * 64);  // prefetch under compute
    const char* bK = pK + cur * 8192;
    const char* bV = pV + cur * 8192;
    const bool g0on = (t <= q0);

    // QK^T for both groups, sharing K fragments (per-kk to limit VGPR)
    f32x4 s0[4] = {}, s1[4] = {};
#pragma unroll
    for (int kk = 0; kk < 2; ++kk) {
      h8 kfx[4];
#pragma unroll
      for (int ni = 0; ni < 4; ++ni) {
        int row = ni * 16 + c;
        kfx[ni] = *(const h8*)(bK + ((row * 128 + kk * 64 + g * 16) ^ sw));
      }
      __builtin_amdgcn_s_setprio(1);
#pragma unroll
      for (int ni = 0; ni < 4; ++ni)
        s1[ni] = __builtin_amdgcn_mfma_f32_16x16x32_f16(kfx[ni], qf[1][kk], s1[ni], 0, 0, 0);
      if (g0on)
#pragma unroll
        for (int ni = 0; ni < 4; ++ni)
          s0[ni] = __builtin_amdgcn_mfma_f32_16x16x32_f16(kfx[ni], qf[0][kk], s0[ni], 0, 0, 0);
      __builtin_amdgcn_s_setprio(0);
    }

    // per-group: softmax + P pack/write + PV  (lane owns q-col = c)
    auto dogroup = [&](f32x4(&s)[4], f32x4(&og)[4], float& mm, float& ll, bool diag) {
      if (diag) {
#pragma unroll
        for (int ni = 0; ni < 4; ++ni)
#pragma unroll
          for (int r = 0; r < 4; ++r) {
            int kv = ni * 16 + g * 4 + r;
            if (kv > w * 16 + c) s[ni][r] = -1e30f;
          }
      }
      // tree max (per-lane over its 16 kv values)
      float m4[4];
#pragma unroll
      for (int ni = 0; ni < 4; ++ni)
        m4[ni] = fmaxf(fmaxf(s[ni][0], s[ni][1]), fmaxf(s[ni][2], s[ni][3]));
      float pmax = fmaxf(fmaxf(m4[0], m4[1]), fmaxf(m4[2], m4[3]));
      // defer-max: common path needs NO cross-lane reduce
      if (!__all(pmax <= mm + 8.f)) {
        float rm = fmaxf(pmax, __shfl_xor(pmax, 16));
        rm = fmaxf(rm, __shfl_xor(rm, 32));
        float mn = fmaxf(mm, rm);
        float al = __builtin_amdgcn_exp2f(mm - mn);
        mm = mn;
        ll *= al;
#pragma unroll
        for (int r = 0; r < 4; ++r) {
          float alr = __shfl(al, g * 4 + r);
#pragma unroll
          for (int nd = 0; nd < 4; ++nd) og[nd][r] *= alr;
        }
      }
      const float mn = mm;
      float rs = 0.f;
#pragma unroll
      for (int ni = 0; ni < 4; ++ni) {
        float e0 = __builtin_amdgcn_exp2f(s[ni][0] - mn);
        float e1 = __builtin_amdgcn_exp2f(s[ni][1] - mn);
        float e2 = __builtin_amdgcn_exp2f(s[ni][2] - mn);
        float e3 = __builtin_amdgcn_exp2f(s[ni][3] - mn);
        rs += (e0 + e1) + (e2 + e3);
        h2 lo = __builtin_bit_cast(h2, __builtin_amdgcn_cvt_pkrtz(e0, e1));
        h2 hi = __builtin_bit_cast(h2, __builtin_amdgcn_cvt_pkrtz(e2, e3));
        h4 pk4 = {lo[0], lo[1], hi[0], hi[1]};
        int off = w * 2048 + c * 128 + ni * 32 + g * 8;
        *(h4*)(pP + (off ^ sw)) = pk4;
      }
      ll += rs;  // per-lane partial; cross-lane reduce deferred to epilogue

      // O += P V (same-wave LDS RAW ordered by lgkmcnt)
#pragma unroll
      for (int kk = 0; kk < 2; ++kk) {
        h8 pf = *(const h8*)(pP + ((w * 2048 + c * 128 + kk * 64 + g * 16) ^ sw));
        h8 vf[4];
#pragma unroll
        for (int nd = 0; nd < 4; ++nd) {
          int row = nd * 16 + c;
          vf[nd] = *(const h8*)(bV + ((row * 128 + kk * 64 + g * 16) ^ sw));
        }
        __builtin_amdgcn_s_setprio(1);
#pragma unroll
        for (int nd = 0; nd < 4; ++nd)
          og[nd] = __builtin_amdgcn_mfma_f32_16x16x32_f16(pf, vf[nd], og[nd], 0, 0, 0);
        __builtin_amdgcn_s_setprio(0);
      }
    };

    if (g0on) dogroup(s0, o0, m0v, l0v, t == q0);
    dogroup(s1, o1, m1v, l1v, t == q1);

    __syncthreads();  // stage(t+1) drained; all waves done reading buf[cur]
  }

  // epilogue per group: reduce per-lane l across the 4 g-lanes of each row
  auto epi = [&](f32x4(&og)[4], float ll, int qsub) {
    float lt = ll + __shfl_xor(ll, 16);
    lt += __shfl_xor(lt, 32);
    float linv = 1.0f / lt;  // valid at lanes with this row's q = c
#pragma unroll
    for (int r = 0; r < 4; ++r) {
      float inv = __shfl(linv, g * 4 + r);
      int qrow = qsub * 64 + w * 16 + g * 4 + r;
#pragma unroll
      for (int nd = 0; nd < 4; ++nd) {
        int col = hI * 64 + nd * 16 + c;
        vals[((size_t)bI * S_ + qrow) * D_ + col] = (_Float16)(og[nd][r] * inv);
      }
    }
  };
  epi(o0, l0v, q0);
  epi(o1, l1v, q1);
}

extern "C" void kernel_launch(void* const* d_in, const int* in_sizes, int n_in,
                              void* d_out, int out_size, void* d_ws, size_t ws_size,
                              hipStream_t stream) {
  const float* x  = (const float*)d_in[0];
  // d_in[1] = mask (fixed causal tril) — hardcoded in attn_fwd
  const float* Wq = (const float*)d_in[2];
  const float* bq = (const float*)d_in[3];
  const float* Wk = (const float*)d_in[4];
  const float* bk = (const float*)d_in[5];
  const float* Wv = (const float*)d_in[6];
  const float* bv = (const float*)d_in[7];
  const float* Wo = (const float*)d_in[8];
  const float* bo = (const float*)d_in[9];
  float* out = (float*)d_out;

  char* ws = (char*)d_ws;
  size_t off = 0;
  auto alloc = [&](size_t bytes) {
    char* p = ws + off;
    off += (bytes + 255) & ~(size_t)255;
    return p;
  };
  _Float16* xb   = (_Float16*)alloc((size_t)B_ * S_ * D_ * 2);           // 16MB
  _Float16* wqkv = (_Float16*)alloc((size_t)3 * D_ * D_ * 2);            // 6MB
  _Float16* wob  = (_Float16*)alloc((size_t)D_ * D_ * 2);                // 2MB
  float*    bqkv = (float*)alloc((size_t)3 * D_ * 4);                    // 12KB
  _Float16* qkvw = (_Float16*)alloc((size_t)2 * B_ * H_ * S_ * DK_ * 2); // 32MB (Q,K)
  _Float16* Vtw  = (_Float16*)alloc((size_t)B_ * H_ * S_ * DK_ * 2);     // 16MB
  _Float16* valw = (_Float16*)alloc((size_t)B_ * S_ * D_ * 2);           // 16MB

  const int nx8 = B_ * S_ * D_ / 8;
  conv_f16<<<(nx8 + 255) / 256, 256, 0, stream>>>(x, xb, nx8);
  conv_weights<<<2048, 256, 0, stream>>>(Wq, Wk, Wv, Wo, bq, bk, bv, wqkv, wob, bqkv);

  // fused QKV projection; V written transposed straight to Vtw
  gemm_nt<0><<<dim3(24, 64), 256, 0, stream>>>(xb, wqkv, bqkv, qkvw, Vtw);

  attn_fwd<<<1024, 256, 0, stream>>>(qkvw, qkvw + (size_t)8388608, Vtw, valw);

  gemm_nt<1><<<dim3(8, 64), 256, 0, stream>>>(valw, wob, bo, out, nullptr);
}

// Round 6
// 191.868 us; speedup vs baseline: 1.9094x; 1.0146x over previous
//
#include <hip/hip_runtime.h>
#include <hip/hip_bf16.h>
#include <cstdint>

#define B_ 4
#define S_ 2048
#define D_ 1024
#define H_ 16
#define DK_ 64

typedef _Float16 h8 __attribute__((ext_vector_type(8)));
typedef _Float16 h4 __attribute__((ext_vector_type(4)));
typedef _Float16 h2 __attribute__((ext_vector_type(2)));
typedef float f32x4 __attribute__((ext_vector_type(4)));
typedef unsigned int u32x4 __attribute__((ext_vector_type(4)));

// async global->LDS, 16B per lane. LDS dest = wave-uniform base + lane*16.
__device__ __forceinline__ void gload16(const void* src, void* lds) {
  __builtin_amdgcn_global_load_lds((const __attribute__((address_space(1))) void*)src,
                                   (__attribute__((address_space(3))) void*)lds, 16, 0, 0);
}

// ---------------- fused convert: x->f16, weights->f16 (QKV concat), bias ----
__global__ __launch_bounds__(256) void conv_all(
    const float* __restrict__ x,
    const float* __restrict__ Wq, const float* __restrict__ Wk,
    const float* __restrict__ Wv, const float* __restrict__ Wo,
    const float* __restrict__ bq, const float* __restrict__ bk,
    const float* __restrict__ bv,
    _Float16* __restrict__ xb, _Float16* __restrict__ wqkv,
    _Float16* __restrict__ wo, float* __restrict__ bqkv) {
  const int bid = blockIdx.x, tid = threadIdx.x;
  if (bid < 4096) {  // x: 8.39M f32, 8 per thread
    int base = (bid * 256 + tid) * 8;
    h8 o;
#pragma unroll
    for (int j = 0; j < 8; ++j) o[j] = (_Float16)x[base + j];
    *(h8*)(xb + base) = o;
  } else {  // weights: 4 x 1M f32, 8 per thread
    int i = (bid - 4096) * 256 + tid;
    int seg = i >> 17, r = i & 131071;
    const float* src = seg == 0 ? Wq : seg == 1 ? Wk : seg == 2 ? Wv : Wo;
    int base = r * 8;
    h8 o;
#pragma unroll
    for (int j = 0; j < 8; ++j) o[j] = (_Float16)src[base + j];
    if (seg < 3)
      *(h8*)(wqkv + (size_t)seg * 1048576 + base) = o;
    else
      *(h8*)(wo + base) = o;
    if (i < 768) {  // bias concat: 3 x 1024 f32
      int bsel = i >> 8, k = (i & 255) * 4;
      const float* bs = bsel == 0 ? bq : bsel == 1 ? bk : bv;
      float4 v = *(const float4*)(bs + k);
      *(float4*)(bqkv + bsel * 1024 + k) = v;
    }
  }
}

// ---------------- NT GEMM: C[m,n] = sum_k A[m,k]*Bw[n,k] + bias[n] -----------
// MODE 0: N=3072 fused QKV; Q,K segments -> [2][B,H,S,DK] f16 at Cout;
//         V segment written TRANSPOSED -> Vt [B,H,DK,S] f16 (h4 packed stores).
// MODE 1: N=1024, f32 out [M][1024].
template <int MODE>
__global__ __launch_bounds__(256) void gemm_nt(const _Float16* __restrict__ A,
                                               const _Float16* __restrict__ Bw,
                                               const float* __restrict__ bias,
                                               void* __restrict__ Cout,
                                               _Float16* __restrict__ Vt) {
  constexpr int K = D_;  // 1024
  __shared__ unsigned short lds[2 * 128 * 64];
  char* ldsA = (char*)lds;
  char* ldsB = (char*)(lds + 128 * 64);

  const int tid = threadIdx.x;
  const int w = tid >> 6, lane = tid & 63, g = lane >> 4, c = lane & 15;
  const int wr = w >> 1, wc = w & 1;
  const int bn = blockIdx.x;  // N/128
  const int bm = blockIdx.y;  // M/128 = 64

  f32x4 acc[4][4] = {};

  const int srow = tid >> 3;
  const int scolsw = ((tid & 7) * 16) ^ ((srow & 7) << 4);  // inverse-swizzled src col
  const char* Ab = (const char*)(A + (size_t)bm * 128 * K);
  const char* Bb = (const char*)(Bw + (size_t)bn * 128 * K);
  const char* Asrc[4];
  const char* Bsrc[4];
#pragma unroll
  for (int j = 0; j < 4; ++j) {
    int row = j * 32 + srow;
    Asrc[j] = Ab + (size_t)row * (K * 2) + scolsw;
    Bsrc[j] = Bb + (size_t)row * (K * 2) + scolsw;
  }
  char* dstA = ldsA + w * 1024;
  char* dstB = ldsB + w * 1024;

  for (int k0 = 0; k0 < K; k0 += 64) {
    __syncthreads();
#pragma unroll
    for (int j = 0; j < 4; ++j) {
      gload16(Asrc[j] + k0 * 2, dstA + j * 4096);
      gload16(Bsrc[j] + k0 * 2, dstB + j * 4096);
    }
    __syncthreads();
#pragma unroll
    for (int kk = 0; kk < 2; ++kk) {
      h8 a[4], b[4];
#pragma unroll
      for (int mi = 0; mi < 4; ++mi) {
        int row = wr * 64 + mi * 16 + c;
        int off = row * 128 + kk * 64 + g * 16;
        a[mi] = *(const h8*)(ldsA + (off ^ ((row & 7) << 4)));
      }
#pragma unroll
      for (int ni = 0; ni < 4; ++ni) {
        int row = wc * 64 + ni * 16 + c;
        int off = row * 128 + kk * 64 + g * 16;
        b[ni] = *(const h8*)(ldsB + (off ^ ((row & 7) << 4)));
      }
      __builtin_amdgcn_s_setprio(1);
#pragma unroll
      for (int mi = 0; mi < 4; ++mi)
#pragma unroll
        for (int ni = 0; ni < 4; ++ni)
          acc[mi][ni] = __builtin_amdgcn_mfma_f32_16x16x32_f16(a[mi], b[ni], acc[mi][ni], 0, 0, 0);
      __builtin_amdgcn_s_setprio(0);
    }
  }

  if (MODE == 0 && bn >= 16) {
    // V segment -> Vt [bh][dk][s]: 4 consecutive s rows pack into one h4 store
#pragma unroll
    for (int mi = 0; mi < 4; ++mi)
#pragma unroll
      for (int ni = 0; ni < 4; ++ni) {
        int m0 = bm * 128 + wr * 64 + mi * 16 + g * 4;
        int n = bn * 128 + wc * 64 + ni * 16 + c;
        float bb = bias[n];
        h4 v4;
#pragma unroll
        for (int r = 0; r < 4; ++r) v4[r] = (_Float16)(acc[mi][ni][r] + bb);
        int bI = m0 >> 11, sI = m0 & 2047;
        int dk = n & 63, hh = (n >> 6) & 15;
        *(h4*)(Vt + (((size_t)(bI * 16 + hh) * 64 + dk) * 2048 + sI)) = v4;
      }
  } else {
#pragma unroll
    for (int mi = 0; mi < 4; ++mi)
#pragma unroll
      for (int ni = 0; ni < 4; ++ni)
#pragma unroll
        for (int r = 0; r < 4; ++r) {
          int m = bm * 128 + wr * 64 + mi * 16 + g * 4 + r;
          int n = bn * 128 + wc * 64 + ni * 16 + c;
          float v = acc[mi][ni][r] + bias[n];
          if (MODE == 0) {
            int which = n >> 10, nn = n & 1023;
            int bI = m >> 11, sI = m & 2047, hI = nn >> 6, dkI = nn & 63;
            ((_Float16*)Cout)[(size_t)which * 8388608 +
                              (((size_t)bI * H_ + hI) * S_ + sI) * DK_ + dkI] = (_Float16)v;
          } else {
            ((float*)Cout)[(size_t)m * D_ + n] = v;
          }
        }
  }
}

// ---------------- causal flash attention ------------------------------------
// Two sequential phases per block (q-subtiles pi and 31-pi -> uniform 33 KV
// tiles/block, short serial chain per barrier). Swapped QK^T (lane owns one
// q-col), vcmp-only defer-max (no shfl common path), per-lane deferred
// l-reduce, cvt_pkrtz P pack interleaved with PV, gload_lds double-buffer,
// bh-inner block mapping (per-XCD K/V L2 residency), T5 setprio.
__global__ __launch_bounds__(256) void attn_fwd(const _Float16* __restrict__ Q,
                                                const _Float16* __restrict__ K,
                                                const _Float16* __restrict__ Vt,
                                                _Float16* __restrict__ vals) {
  __shared__ unsigned short ldsK[2 * 64 * 64];  // 16KB
  __shared__ unsigned short ldsV[2 * 64 * 64];  // 16KB
  __shared__ unsigned short ldsP[4 * 16 * 64];  // 8KB
  char* pK = (char*)ldsK;
  char* pV = (char*)ldsV;
  char* pP = (char*)ldsP;

  const int tid = threadIdx.x;
  const int w = tid >> 6, lane = tid & 63, g = lane >> 4, c = lane & 15;
  const int bid = blockIdx.x;
  const int pi = bid >> 6;   // 0..15
  const int bh = bid & 63;   // bh-inner: each XCD sees bh = xcd (mod 8) -> L2-resident K/V
  const int bI = bh >> 4, hI = bh & 15;
  const int q0 = pi, q1 = 31 - pi;

  const char* Qb = (const char*)(Q + (size_t)bh * S_ * DK_);
  const char* Kb = (const char*)(K + (size_t)bh * S_ * DK_);
  const char* Vtb = (const char*)(Vt + (size_t)bh * DK_ * S_);

  const int srow = tid >> 3;
  const int scol = (tid & 7) * 16;
  int offK[2], offV[2];
#pragma unroll
  for (int j = 0; j < 2; ++j) {
    int row = j * 32 + srow;
    int colsw = scol ^ ((row & 7) << 4);
    offK[j] = row * 128 + colsw;   // K tile contiguous [64][128B]
    offV[j] = row * 4096 + colsw;  // Vt row stride = S*2 = 4096B
  }
  char* dstK = pK + w * 1024;
  char* dstV = pV + w * 1024;

  auto stage = [&](int buf, int kv0) {
#pragma unroll
    for (int j = 0; j < 2; ++j) {
      gload16(Kb + (size_t)kv0 * 128 + offK[j], dstK + buf * 8192 + j * 4096);
      gload16(Vtb + (size_t)kv0 * 2 + offV[j], dstV + buf * 8192 + j * 4096);
    }
  };

  const _Float16 qsc = (_Float16)(0.125f * 1.44269504f);  // scale * log2(e)
  const int sw = (c & 7) << 4;

  for (int phase = 0; phase < 2; ++phase) {
    const int qsub = (phase == 0) ? q0 : q1;
    const int qw0 = qsub * 64 + w * 16;

    h8 qf[2];
#pragma unroll
    for (int kk = 0; kk < 2; ++kk) {
      h8 v = *(const h8*)(Qb + (size_t)(qw0 + c) * 128 + kk * 64 + g * 16);
#pragma unroll
      for (int j = 0; j < 8; ++j) v[j] *= qsc;
      qf[kk] = v;
    }

    f32x4 o[4] = {};
    float m_ = -1e30f, l_ = 0.f;

    const int nt = qsub + 1;
    stage(0, 0);
    __syncthreads();  // buf0 ready (vmcnt drained at barrier)

    for (int t = 0; t < nt; ++t) {
      const int cur = t & 1;
      if (t + 1 < nt) stage(cur ^ 1, (t + 1) * 64);  // prefetch under compute
      const char* bK = pK + cur * 8192;
      const char* bV = pV + cur * 8192;

      // S^T = K Q^T : col = q = c, row = kv = ni*16 + g*4 + r
      f32x4 s[4] = {};
#pragma unroll
      for (int kk = 0; kk < 2; ++kk) {
        h8 kfx[4];
#pragma unroll
        for (int ni = 0; ni < 4; ++ni) {
          int row = ni * 16 + c;
          kfx[ni] = *(const h8*)(bK + ((row * 128 + kk * 64 + g * 16) ^ sw));
        }
        __builtin_amdgcn_s_setprio(1);
#pragma unroll
        for (int ni = 0; ni < 4; ++ni)
          s[ni] = __builtin_amdgcn_mfma_f32_16x16x32_f16(kfx[ni], qf[kk], s[ni], 0, 0, 0);
        __builtin_amdgcn_s_setprio(0);
      }

      // causal mask: diagonal tile only (block-uniform branch)
      if (t == nt - 1) {
#pragma unroll
        for (int ni = 0; ni < 4; ++ni)
#pragma unroll
          for (int r = 0; r < 4; ++r) {
            int kv = ni * 16 + g * 4 + r;
            if (kv > w * 16 + c) s[ni][r] = -1e30f;
          }
      }

      // tree max (per-lane over its 16 kv values)
      float m4[4];
#pragma unroll
      for (int ni = 0; ni < 4; ++ni)
        m4[ni] = fmaxf(fmaxf(s[ni][0], s[ni][1]), fmaxf(s[ni][2], s[ni][3]));
      float pmax = fmaxf(fmaxf(m4[0], m4[1]), fmaxf(m4[2], m4[3]));
      // defer-max: common path needs NO cross-lane reduce
      if (!__all(pmax <= m_ + 8.f)) {
        float rm = fmaxf(pmax, __shfl_xor(pmax, 16));
        rm = fmaxf(rm, __shfl_xor(rm, 32));
        float mn = fmaxf(m_, rm);
        float al = __builtin_amdgcn_exp2f(m_ - mn);
        m_ = mn;
        l_ *= al;
#pragma unroll
        for (int r = 0; r < 4; ++r) {
          float alr = __shfl(al, g * 4 + r);
#pragma unroll
          for (int nd = 0; nd < 4; ++nd) o[nd][r] *= alr;
        }
      }
      const float mn = m_;
      float rs = 0.f;

      // exp + pack + P write for kv 0..31 (ni 0,1), then PV kk=0 overlaps
      // with exp of kv 32..63 (ni 2,3), then PV kk=1.
#pragma unroll
      for (int ni = 0; ni < 2; ++ni) {
        float e0 = __builtin_amdgcn_exp2f(s[ni][0] - mn);
        float e1 = __builtin_amdgcn_exp2f(s[ni][1] - mn);
        float e2 = __builtin_amdgcn_exp2f(s[ni][2] - mn);
        float e3 = __builtin_amdgcn_exp2f(s[ni][3] - mn);
        rs += (e0 + e1) + (e2 + e3);
        h2 lo = __builtin_bit_cast(h2, __builtin_amdgcn_cvt_pkrtz(e0, e1));
        h2 hi = __builtin_bit_cast(h2, __builtin_amdgcn_cvt_pkrtz(e2, e3));
        h4 pk4 = {lo[0], lo[1], hi[0], hi[1]};
        int off = w * 2048 + c * 128 + ni * 32 + g * 8;
        *(h4*)(pP + (off ^ sw)) = pk4;
      }
      {
        h8 pf = *(const h8*)(pP + ((w * 2048 + c * 128 + g * 16) ^ sw));
        h8 vf[4];
#pragma unroll
        for (int nd = 0; nd < 4; ++nd) {
          int row = nd * 16 + c;
          vf[nd] = *(const h8*)(bV + ((row * 128 + g * 16) ^ sw));
        }
        __builtin_amdgcn_s_setprio(1);
#pragma unroll
        for (int nd = 0; nd < 4; ++nd)
          o[nd] = __builtin_amdgcn_mfma_f32_16x16x32_f16(pf, vf[nd], o[nd], 0, 0, 0);
        __builtin_amdgcn_s_setprio(0);
      }
#pragma unroll
      for (int ni = 2; ni < 4; ++ni) {
        float e0 = __builtin_amdgcn_exp2f(s[ni][0] - mn);
        float e1 = __builtin_amdgcn_exp2f(s[ni][1] - mn);
        float e2 = __builtin_amdgcn_exp2f(s[ni][2] - mn);
        float e3 = __builtin_amdgcn_exp2f(s[ni][3] - mn);
        rs += (e0 + e1) + (e2 + e3);
        h2 lo = __builtin_bit_cast(h2, __builtin_amdgcn_cvt_pkrtz(e0, e1));
        h2 hi = __builtin_bit_cast(h2, __builtin_amdgcn_cvt_pkrtz(e2, e3));
        h4 pk4 = {lo[0], lo[1], hi[0], hi[1]};
        int off = w * 2048 + c * 128 + ni * 32 + g * 8;
        *(h4*)(pP + (off ^ sw)) = pk4;
      }
      {
        h8 pf = *(const h8*)(pP + ((w * 2048 + c * 128 + 64 + g * 16) ^ sw));
        h8 vf[4];
#pragma unroll
        for (int nd = 0; nd < 4; ++nd) {
          int row = nd * 16 + c;
          vf[nd] = *(const h8*)(bV + ((row * 128 + 64 + g * 16) ^ sw));
        }
        __builtin_amdgcn_s_setprio(1);
#pragma unroll
        for (int nd = 0; nd < 4; ++nd)
          o[nd] = __builtin_amdgcn_mfma_f32_16x16x32_f16(pf, vf[nd], o[nd], 0, 0, 0);
        __builtin_amdgcn_s_setprio(0);
      }
      l_ += rs;  // per-lane partial; cross-lane reduce deferred to epilogue

      __syncthreads();  // stage(t+1) drained; all waves done reading buf[cur]
    }

    // epilogue: reduce per-lane l across the 4 g-lanes of each row
    float lt = l_ + __shfl_xor(l_, 16);
    lt += __shfl_xor(lt, 32);
    float linv = 1.0f / lt;  // valid at lanes whose c == row's q
#pragma unroll
    for (int r = 0; r < 4; ++r) {
      float inv = __shfl(linv, g * 4 + r);
      int qrow = qsub * 64 + w * 16 + g * 4 + r;
#pragma unroll
      for (int nd = 0; nd < 4; ++nd) {
        int col = hI * 64 + nd * 16 + c;
        vals[((size_t)bI * S_ + qrow) * D_ + col] = (_Float16)(o[nd][r] * inv);
      }
    }
  }
}

extern "C" void kernel_launch(void* const* d_in, const int* in_sizes, int n_in,
                              void* d_out, int out_size, void* d_ws, size_t ws_size,
                              hipStream_t stream) {
  const float* x  = (const float*)d_in[0];
  // d_in[1] = mask (fixed causal tril) — hardcoded in attn_fwd
  const float* Wq = (const float*)d_in[2];
  const float* bq = (const float*)d_in[3];
  const float* Wk = (const float*)d_in[4];
  const float* bk = (const float*)d_in[5];
  const float* Wv = (const float*)d_in[6];
  const float* bv = (const float*)d_in[7];
  const float* Wo = (const float*)d_in[8];
  const float* bo = (const float*)d_in[9];
  float* out = (float*)d_out;

  char* ws = (char*)d_ws;
  size_t off = 0;
  auto alloc = [&](size_t bytes) {
    char* p = ws + off;
    off += (bytes + 255) & ~(size_t)255;
    return p;
  };
  _Float16* xb   = (_Float16*)alloc((size_t)B_ * S_ * D_ * 2);           // 16MB
  _Float16* wqkv = (_Float16*)alloc((size_t)3 * D_ * D_ * 2);            // 6MB
  _Float16* wob  = (_Float16*)alloc((size_t)D_ * D_ * 2);                // 2MB
  float*    bqkv = (float*)alloc((size_t)3 * D_ * 4);                    // 12KB
  _Float16* qkvw = (_Float16*)alloc((size_t)2 * B_ * H_ * S_ * DK_ * 2); // 32MB (Q,K)
  _Float16* Vtw  = (_Float16*)alloc((size_t)B_ * H_ * S_ * DK_ * 2);     // 16MB
  _Float16* valw = (_Float16*)alloc((size_t)B_ * S_ * D_ * 2);           // 16MB

  conv_all<<<6144, 256, 0, stream>>>(x, Wq, Wk, Wv, Wo, bq, bk, bv, xb, wqkv, wob, bqkv);

  // fused QKV projection; V written transposed straight to Vtw
  gemm_nt<0><<<dim3(24, 64), 256, 0, stream>>>(xb, wqkv, bqkv, qkvw, Vtw);

  attn_fwd<<<1024, 256, 0, stream>>>(qkvw, qkvw + (size_t)8388608, Vtw, valw);

  gemm_nt<1><<<dim3(8, 64), 256, 0, stream>>>(valw, wob, bo, out, nullptr);
}